// Round 8
// baseline (310.218 us; speedup 1.0000x reference)
//
#include <hip/hip_runtime.h>
#include <hip/hip_fp16.h>
#include <cmath>

#define NROWS  65536
#define DIM    512
#define KCODES 2048
#define NDTOT  33554432LL   // NROWS*DIM
// refine trigger: f16-product error (14*sigma = 0.0625) + key truncation (<=0.5)
#define MARGIN_P 0.5625f

typedef __attribute__((ext_vector_type(8))) _Float16 f16x8;  // 8 f16 = 1 MFMA operand
typedef __attribute__((ext_vector_type(4))) float f32x4;

// branchless sorted-top3 insert of packed key v (u32 min/max keep regs, no addresses)
#define KINS3(K1,K2,K3,V) do {                       \
    unsigned int _v = (V);                           \
    unsigned int _h1 = max((K1), _v); (K1) = min((K1), _v); \
    unsigned int _h2 = max((K2), _h1); (K2) = min((K2), _h1); \
    (K3) = min((K3), _h2);                           \
} while (0)

// in-place merge of two sorted triples (A <- merge(A,B)), packed-key order
#define MRG3(A1,A2,A3,B1,B2,B3) do {                               \
    unsigned int _x1 = min((A1),(B1)), _y1 = max((A1),(B1));       \
    unsigned int _x2 = min((A2),(B2)), _y2 = max((A2),(B2));       \
    unsigned int _x3 = min((A3),(B3));                             \
    (A1) = _x1; (A2) = min(_y1,_x2);                               \
    (A3) = min(max(_y1,_x2), min(_x3,_y2));                        \
} while (0)

__device__ inline void gll16(const void* g, void* l) {
    __builtin_amdgcn_global_load_lds(
        (const __attribute__((address_space(1))) void*)g,
        (__attribute__((address_space(3))) void*)l, 16, 0, 0);
}

// ---------------- kernel 1: fp32 -> f16 plane in fragment-lane order, fused row norm ----
// tile (per 128-row block rb, per ks64 of 64 dims): 16384 B =
//   [ksub 2][frow 8][lane 64][16B]; lane = (k32sub)*16 + row%16, frow=(row%128)/16.
// Matches mfma_f32_16x16x32_f16 A/B frags (lane l: row l&15, k=(l>>4)*8+r).
__global__ __launch_bounds__(256) void k_prep(const float* __restrict__ src,
                                              char* __restrict__ dst,
                                              float* __restrict__ norms) {
    long gid = (long)blockIdx.x * 256 + threadIdx.x;
    int row = (int)(gid >> 6);
    int k8  = (int)(gid & 63);           // chunk of 8 dims
    const float4* s = (const float4*)(src + (size_t)row * DIM + k8 * 8);
    float4 v0 = s[0], v1 = s[1];
    float vv[8] = {v0.x, v0.y, v0.z, v0.w, v1.x, v1.y, v1.z, v1.w};
    unsigned int hw[4];
    float nrm = 0.f;
    #pragma unroll
    for (int j = 0; j < 4; ++j) {
        unsigned int h0 = __half_as_ushort(__float2half_rn(vv[2*j]));
        unsigned int h1 = __half_as_ushort(__float2half_rn(vv[2*j+1]));
        hw[j] = h0 | (h1 << 16);
        nrm = fmaf(vv[2*j], vv[2*j], nrm);
        nrm = fmaf(vv[2*j+1], vv[2*j+1], nrm);
    }
    int rb = row >> 7, frow = (row >> 4) & 7;
    int k32 = k8 >> 2, sub = k8 & 3;
    int ksub = k32 & 1, ks64 = k32 >> 1;
    int l = sub * 16 + (row & 15);
    size_t off = (size_t)(rb * 8 + ks64) * 16384 + (size_t)ksub * 8192
               + (size_t)frow * 1024 + (size_t)l * 16;
    *(uint4*)(dst + off) = make_uint4(hw[0], hw[1], hw[2], hw[3]);
    #pragma unroll
    for (int o = 32; o; o >>= 1) nrm += __shfl_xor(nrm, o, 64);
    if ((threadIdx.x & 63) == 0) norms[row] = nrm;
}

// ---------------- kernel 2: f16 MFMA GEMM, A LDS-resident, fused packed top-3 ----------
// 512 blocks x 512 threads (8 waves, 1 block/CU at 160KB LDS).
// smem: A (whole 128-row slab, 128KB, staged ONCE) + B dbuf 2x16KB.
// Loop t=0..127 over (cb 16 x ks 8); only B staged per step -> MFMA-bound.
__global__ __launch_bounds__(512, 1) void k_gemm(const char* __restrict__ xp,
                                                 const char* __restrict__ wp,
                                                 const float* __restrict__ wnorm,
                                                 int* __restrict__ idxo,
                                                 int* __restrict__ cand2o,
                                                 int* __restrict__ cand3o,
                                                 float* __restrict__ bestd) {
    __shared__ char smem[163840];   // A @0 (131072) ; Bs[2] @131072,147456
    const int tid = threadIdx.x;
    const int lane = tid & 63;
    const int wid = tid >> 6;          // 0..7
    const int wr = wid >> 2, wc = wid & 3;   // wave grid 2 x 4, wave-tile 64x32
    const int rb = blockIdx.x;
    const char* xsrc = xp + (size_t)rb * 131072;

    f32x4 acc[4][2];
    #pragma unroll
    for (int i = 0; i < 4; ++i)
        #pragma unroll
        for (int j = 0; j < 2; ++j) acc[i][j] = (f32x4){0.f, 0.f, 0.f, 0.f};

    unsigned int k1[16], k2[16], k3[16];
    #pragma unroll
    for (int s = 0; s < 16; ++s) { k1[s] = k2[s] = k3[s] = 0xFFFFFFFFu; }

    // prologue: stage the whole A slab (xp layout == LDS layout, linear copy)
    #pragma unroll
    for (int i = 0; i < 16; ++i) {
        int c = wid * 16 + i;          // 128 chunks of 1024B
        gll16(xsrc + c * 1024 + lane * 16, smem + c * 1024);
    }
    // stage B tile 0
    gll16(wp + (wid * 2 + 0) * 1024 + lane * 16, smem + 131072 + (wid * 2 + 0) * 1024);
    gll16(wp + (wid * 2 + 1) * 1024 + lane * 16, smem + 131072 + (wid * 2 + 1) * 1024);
    __syncthreads();

    #pragma unroll 2
    for (int t = 0; t < 128; ++t) {
        int p = t & 1;
        if (t < 127) {                 // stage B(t+1) into the other buffer
            const char* bsrc = wp + (size_t)(t + 1) * 16384;
            char* bdst = smem + 131072 + (p ^ 1) * 16384;
            gll16(bsrc + (wid * 2 + 0) * 1024 + lane * 16, bdst + (wid * 2 + 0) * 1024);
            gll16(bsrc + (wid * 2 + 1) * 1024 + lane * 16, bdst + (wid * 2 + 1) * 1024);
        }
        const char* A = smem + (t & 7) * 16384;
        const char* B = smem + 131072 + p * 16384;
        #pragma unroll
        for (int ksub = 0; ksub < 2; ++ksub) {
            f16x8 ah[4];
            #pragma unroll
            for (int fr = 0; fr < 4; ++fr)
                ah[fr] = *(const f16x8*)(A + ksub * 8192 + (wr * 4 + fr) * 1024 + lane * 16);
            #pragma unroll
            for (int fc = 0; fc < 2; ++fc) {
                f16x8 bh = *(const f16x8*)(B + ksub * 8192 + (wc * 2 + fc) * 1024 + lane * 16);
                #pragma unroll
                for (int fr = 0; fr < 4; ++fr)
                    acc[fr][fc] = __builtin_amdgcn_mfma_f32_16x16x32_f16(ah[fr], bh, acc[fr][fc], 0, 0, 0);
            }
        }
        if ((t & 7) == 7) {            // end of cb pass: top-3 update, reset acc
            int cb = t >> 3;
            #pragma unroll
            for (int fc = 0; fc < 2; ++fc) {
                unsigned int col = (unsigned)(cb * 128 + wc * 32 + fc * 16 + (lane & 15));
                float wnb = wnorm[col] + 1024.f;   // bias keeps key positive, exp band 2^10
                #pragma unroll
                for (int fr = 0; fr < 4; ++fr) {
                    #pragma unroll
                    for (int reg = 0; reg < 4; ++reg) {
                        float kd = fmaf(-2.f, acc[fr][fc][reg], wnb);
                        unsigned int key = (__float_as_uint(kd) & 0xFFFFF800u) | col;
                        int s = fr * 4 + reg;
                        KINS3(k1[s], k2[s], k3[s], key);
                    }
                    acc[fr][fc] = (f32x4){0.f, 0.f, 0.f, 0.f};
                }
            }
        }
        __syncthreads();
    }

    // butterfly top-3 merge across the 16 column-lanes of each slot
    #pragma unroll
    for (int s = 0; s < 16; ++s) {
        #pragma unroll
        for (int off = 1; off < 16; off <<= 1) {
            unsigned int b1 = (unsigned)__shfl_xor((int)k1[s], off, 16);
            unsigned int b2 = (unsigned)__shfl_xor((int)k2[s], off, 16);
            unsigned int b3 = (unsigned)__shfl_xor((int)k3[s], off, 16);
            MRG3(k1[s], k2[s], k3[s], b1, b2, b3);
        }
    }
    // lane (lane&15)==s owns slot s; static-unrolled select (rule #20)
    unsigned int m1 = 0, m2 = 0, m3 = 0;
    #pragma unroll
    for (int s = 0; s < 16; ++s) {
        bool mine = (lane & 15) == s;
        m1 = mine ? k1[s] : m1;
        m2 = mine ? k2[s] : m2;
        m3 = mine ? k3[s] : m3;
    }
    int sl = lane & 15;
    int rowl = wr * 64 + (sl >> 2) * 16 + (lane >> 4) * 4 + (sl & 3);
    ((uint4*)smem)[rowl * 4 + wc] = make_uint4(m1, m2, m3, 0u);   // A region dead
    __syncthreads();
    if (tid < 128) {
        uint4 a = ((const uint4*)smem)[tid * 4 + 0];
        uint4 b = ((const uint4*)smem)[tid * 4 + 1];
        uint4 c = ((const uint4*)smem)[tid * 4 + 2];
        uint4 d = ((const uint4*)smem)[tid * 4 + 3];
        unsigned int K1 = a.x, K2 = a.y, K3 = a.z;
        MRG3(K1, K2, K3, b.x, b.y, b.z);
        MRG3(K1, K2, K3, c.x, c.y, c.z);
        MRG3(K1, K2, K3, d.x, d.y, d.z);
        float f1 = __uint_as_float(K1 & 0xFFFFF800u) - 1024.f;
        float f2 = __uint_as_float(K2 & 0xFFFFF800u) - 1024.f;
        float f3 = __uint_as_float(K3 & 0xFFFFF800u) - 1024.f;
        int row = rb * 128 + tid;
        idxo[row]   = (int)(K1 & 0x7FFu);
        bestd[row]  = f1;
        cand2o[row] = (f2 - f1 < MARGIN_P) ? (int)(K2 & 0x7FFu) : -1;
        cand3o[row] = (f3 - f1 < MARGIN_P) ? (int)(K3 & 0x7FFu) : -1;
    }
}

// ---------------- kernel 3: fused fp64 refine + gather + loss partial + histogram ----
// one wave per row; flagged rows re-resolve up to 3 candidates in fp64.
__global__ __launch_bounds__(256) void k_gather2(const float* __restrict__ x,
                                                 const float* __restrict__ w,
                                                 const int* __restrict__ idxo,
                                                 const int* __restrict__ cand2o,
                                                 const int* __restrict__ cand3o,
                                                 const float* __restrict__ bestd,
                                                 const float* __restrict__ xnorm,
                                                 float* __restrict__ out,
                                                 int* __restrict__ hist,
                                                 double* __restrict__ part) {
    __shared__ double red[4];
    int wid = threadIdx.x >> 6, lane = threadIdx.x & 63;
    int n = blockIdx.x * 4 + wid;
    int c1 = idxo[n];
    int c2 = cand2o[n];
    int cfin = c1;
    double dist = (double)bestd[n];
    if (c2 >= 0) {
        int c3 = cand3o[n];
        int c3e = (c3 < 0) ? c1 : c3;
        const float* xr = x + (size_t)n * DIM;
        const float* w1 = w + (size_t)c1 * DIM;
        const float* w2 = w + (size_t)c2 * DIM;
        const float* w3 = w + (size_t)c3e * DIM;
        double s1 = 0.0, s2 = 0.0, s3 = 0.0;
        #pragma unroll
        for (int j = 0; j < DIM / 64; ++j) {
            int d = lane + 64 * j;
            double xv = (double)xr[d];
            double a = (double)w1[d], b = (double)w2[d], c = (double)w3[d];
            s1 += a * a - 2.0 * xv * a;
            s2 += b * b - 2.0 * xv * b;
            s3 += c * c - 2.0 * xv * c;
        }
        #pragma unroll
        for (int off = 32; off; off >>= 1) {
            s1 += __shfl_xor(s1, off, 64);
            s2 += __shfl_xor(s2, off, 64);
            s3 += __shfl_xor(s3, off, 64);
        }
        double bs = s1; int bi = c1;
        if (s2 < bs || (s2 == bs && c2 < bi)) { bs = s2; bi = c2; }
        if (c3 >= 0 && (s3 < bs || (s3 == bs && c3 < bi))) { bs = s3; bi = c3; }
        cfin = bi;
        dist = bs;
    }
    // gather winner row (uniform across wave)
    const float* wq = w + (size_t)cfin * DIM;
    float* oq = out + 1 + (size_t)n * DIM;   // quantized_st == quantized numerically
    #pragma unroll
    for (int j = 0; j < DIM / 64; ++j) {
        int d = j * 64 + lane;
        oq[d] = wq[d];
    }
    if (lane == 0) {
        red[wid] = dist + (double)xnorm[n];  // ||x-w||^2 = (||w||^2-2xw) + ||x||^2
        atomicAdd(&hist[cfin], 1);
        out[2 + NDTOT + n] = (float)cfin;
    }
    __syncthreads();
    if (threadIdx.x == 0)
        part[blockIdx.x] = red[0] + red[1] + red[2] + red[3];
}

// ---------------- kernel 4: deterministic finalize (loss + perplexity) ----------------
__global__ __launch_bounds__(256) void k_final2(const double* __restrict__ part,
                                                const int* __restrict__ hist,
                                                float* __restrict__ out) {
    __shared__ double sm[256];
    int t = threadIdx.x;
    double s = 0.0;
    for (int i = t; i < NROWS / 4; i += 256) s += part[i];
    sm[t] = s; __syncthreads();
    for (int off = 128; off; off >>= 1) { if (t < off) sm[t] += sm[t + off]; __syncthreads(); }
    if (t == 0) out[0] = (float)(sm[0] * 0.25 / (double)NDTOT);
    __syncthreads();
    double e = 0.0;
    for (int k = t; k < KCODES; k += 256) {
        double p = (double)hist[k] / (double)NROWS;
        e -= p * log(p + 1e-10);
    }
    sm[t] = e; __syncthreads();
    for (int off = 128; off; off >>= 1) { if (t < off) sm[t] += sm[t + off]; __syncthreads(); }
    if (t == 0) out[1 + NDTOT] = (float)exp(sm[0]);
}

extern "C" void kernel_launch(void* const* d_in, const int* in_sizes, int n_in,
                              void* d_out, int out_size, void* d_ws, size_t ws_size,
                              hipStream_t stream) {
    const float* x = (const float*)d_in[0];   // [64,1024,512] fp32
    const float* w = (const float*)d_in[1];   // [2048,512] fp32
    float* out = (float*)d_out;
    char* ws = (char*)d_ws;

    // xp (64 MB f16 fragment-ordered) lives in the d_out quantized region:
    // k_gemm consumes it before k_gather2 overwrites every byte with outputs.
    char* xp = (char*)d_out + 16;

    char*   wp    = ws;                            // 2 MB
    float*  wnorm = (float*)(ws + 2097152);        // 8 KB
    int*    idxo  = (int*)(ws + 2105344);          // 256 KB
    int*    cand2 = (int*)(ws + 2367488);          // 256 KB
    int*    cand3 = (int*)(ws + 2629632);          // 256 KB
    int*    hist  = (int*)(ws + 2891776);          // 8 KB
    float*  xnorm = (float*)(ws + 2899968);        // 256 KB
    float*  bestd = (float*)(ws + 3162112);        // 256 KB
    double* part  = (double*)(ws + 3424256);       // 128 KB

    hipMemsetAsync(hist, 0, KCODES * sizeof(int), stream);
    k_prep   <<<(KCODES * 64) / 256, 256, 0, stream>>>(w, wp, wnorm);
    k_prep   <<<(NROWS * 64) / 256, 256, 0, stream>>>(x, xp, xnorm);
    k_gemm   <<<NROWS / 128, 512, 0, stream>>>(xp, wp, wnorm, idxo, cand2, cand3, bestd);
    k_gather2<<<NROWS / 4, 256, 0, stream>>>(x, w, idxo, cand2, cand3, bestd, xnorm, out, hist, part);
    k_final2 <<<1, 256, 0, stream>>>(part, hist, out);
}

// Round 9
// 274.233 us; speedup vs baseline: 1.1312x; 1.1312x over previous
//
#include <hip/hip_runtime.h>
#include <hip/hip_fp16.h>
#include <cmath>

#define NROWS  65536
#define DIM    512
#define KCODES 2048
#define NDTOT  33554432LL   // NROWS*DIM
// refine trigger: f16-product error (14*sigma = 0.0625) + key truncation (<=0.5)
#define MARGIN_P 0.5625f

typedef __attribute__((ext_vector_type(8))) _Float16 f16x8;  // 8 f16 = 1 MFMA operand
typedef __attribute__((ext_vector_type(4))) float f32x4;

// branchless sorted-top3 insert of packed key v (u32 min/max keep regs, no addresses)
#define KINS3(K1,K2,K3,V) do {                       \
    unsigned int _v = (V);                           \
    unsigned int _h1 = max((K1), _v); (K1) = min((K1), _v); \
    unsigned int _h2 = max((K2), _h1); (K2) = min((K2), _h1); \
    (K3) = min((K3), _h2);                           \
} while (0)

// in-place merge of two sorted triples (A <- merge(A,B)), packed-key order
#define MRG3(A1,A2,A3,B1,B2,B3) do {                               \
    unsigned int _x1 = min((A1),(B1)), _y1 = max((A1),(B1));       \
    unsigned int _x2 = min((A2),(B2)), _y2 = max((A2),(B2));       \
    unsigned int _x3 = min((A3),(B3));                             \
    (A1) = _x1; (A2) = min(_y1,_x2);                               \
    (A3) = min(max(_y1,_x2), min(_x3,_y2));                        \
} while (0)

__device__ inline void gll16(const void* g, void* l) {
    __builtin_amdgcn_global_load_lds(
        (const __attribute__((address_space(1))) void*)g,
        (__attribute__((address_space(3))) void*)l, 16, 0, 0);
}

// ---------------- kernel 1a: x -> f16 fragment-order + row norms (unchanged layout) ----
// per 128-row slab rb: [ks64 8][ksub 2][frow 8][lane 64][16B];
// lane = ((k%32)/8)*16 + row%16, frow = (row%128)/16.
__global__ __launch_bounds__(256) void k_prep(const float* __restrict__ src,
                                              char* __restrict__ dst,
                                              float* __restrict__ norms) {
    long gid = (long)blockIdx.x * 256 + threadIdx.x;
    int row = (int)(gid >> 6);
    int k8  = (int)(gid & 63);           // chunk of 8 dims
    const float4* s = (const float4*)(src + (size_t)row * DIM + k8 * 8);
    float4 v0 = s[0], v1 = s[1];
    float vv[8] = {v0.x, v0.y, v0.z, v0.w, v1.x, v1.y, v1.z, v1.w};
    unsigned int hw[4];
    float nrm = 0.f;
    #pragma unroll
    for (int j = 0; j < 4; ++j) {
        unsigned int h0 = __half_as_ushort(__float2half_rn(vv[2*j]));
        unsigned int h1 = __half_as_ushort(__float2half_rn(vv[2*j+1]));
        hw[j] = h0 | (h1 << 16);
        nrm = fmaf(vv[2*j], vv[2*j], nrm);
        nrm = fmaf(vv[2*j+1], vv[2*j+1], nrm);
    }
    int rb = row >> 7, frow = (row >> 4) & 7;
    int k32 = k8 >> 2, sub = k8 & 3;
    int ksub = k32 & 1, ks64 = k32 >> 1;
    int l = sub * 16 + (row & 15);
    size_t off = (size_t)(rb * 8 + ks64) * 16384 + (size_t)ksub * 8192
               + (size_t)frow * 1024 + (size_t)l * 16;
    *(uint4*)(dst + off) = make_uint4(hw[0], hw[1], hw[2], hw[3]);
    #pragma unroll
    for (int o = 32; o; o >>= 1) nrm += __shfl_xor(nrm, o, 64);
    if ((threadIdx.x & 63) == 0) norms[row] = nrm;
}

// ---------------- kernel 1b: w -> f16 B-tile order + norms ----------------
// tile (cb 8 of 256 cols, ks32 16): 16384 B = [fcol 16][lane 64][16B];
// lane = ((k%32)/8)*16 + col%16, fcol = (col%256)/16. Staged linearly per t.
__global__ __launch_bounds__(256) void k_prepw(const float* __restrict__ src,
                                               char* __restrict__ dst,
                                               float* __restrict__ norms) {
    long gid = (long)blockIdx.x * 256 + threadIdx.x;
    int c  = (int)(gid >> 6);
    int k8 = (int)(gid & 63);
    const float4* s = (const float4*)(src + (size_t)c * DIM + k8 * 8);
    float4 v0 = s[0], v1 = s[1];
    float vv[8] = {v0.x, v0.y, v0.z, v0.w, v1.x, v1.y, v1.z, v1.w};
    unsigned int hw[4];
    float nrm = 0.f;
    #pragma unroll
    for (int j = 0; j < 4; ++j) {
        unsigned int h0 = __half_as_ushort(__float2half_rn(vv[2*j]));
        unsigned int h1 = __half_as_ushort(__float2half_rn(vv[2*j+1]));
        hw[j] = h0 | (h1 << 16);
        nrm = fmaf(vv[2*j], vv[2*j], nrm);
        nrm = fmaf(vv[2*j+1], vv[2*j+1], nrm);
    }
    int cb = c >> 8, fcol = (c >> 4) & 15;
    int ks32 = k8 >> 2, sub = k8 & 3;
    int l = sub * 16 + (c & 15);
    size_t off = (size_t)((cb * 16 + ks32) * 16 + fcol) * 1024 + (size_t)l * 16;
    *(uint4*)(dst + off) = make_uint4(hw[0], hw[1], hw[2], hw[3]);
    #pragma unroll
    for (int o = 32; o; o >>= 1) nrm += __shfl_xor(nrm, o, 64);
    if ((threadIdx.x & 63) == 0) norms[c] = nrm;
}

// ---------------- kernel 2: f16 MFMA GEMM, A LDS-resident, counted-vmcnt pipeline ----
// 512 blocks x 512 threads (8 waves 2x4, 1 block/CU at 160KB LDS).
// smem: A slab 128KB (staged once) + B dbuf 2x16KB. Block tile 128x256,
// wave tile 64x64 (acc[4][4], 512 B LDS-read per MFMA). Loop t = cb*16+ks32.
// T4: stage B(t+1) then s_waitcnt vmcnt(2) (B(t) only) + raw s_barrier —
// no vmcnt(0) drain in the loop (1 block/CU has no overlap partner).
__global__ __launch_bounds__(512, 1) void k_gemm(const char* __restrict__ xp,
                                                 const char* __restrict__ wp,
                                                 const float* __restrict__ wnorm,
                                                 int* __restrict__ idxo,
                                                 int* __restrict__ cand2o,
                                                 int* __restrict__ cand3o,
                                                 float* __restrict__ bestd) {
    __shared__ char smem[163840];   // A @0 (131072) ; Bs[2] @131072,147456
    const int tid = threadIdx.x;
    const int lane = tid & 63;
    const int wid = tid >> 6;                // 0..7
    const int wr = wid >> 2, wc = wid & 3;   // wave grid 2 x 4
    const int rb = blockIdx.x;
    const char* xsrc = xp + (size_t)rb * 131072;

    f32x4 acc[4][4];
    #pragma unroll
    for (int i = 0; i < 4; ++i)
        #pragma unroll
        for (int j = 0; j < 4; ++j) acc[i][j] = (f32x4){0.f, 0.f, 0.f, 0.f};

    unsigned int k1[16], k2[16], k3[16];
    #pragma unroll
    for (int s = 0; s < 16; ++s) { k1[s] = k2[s] = k3[s] = 0xFFFFFFFFu; }

    // prologue: whole A slab (once) + B tile 0
    #pragma unroll
    for (int i = 0; i < 16; ++i) {
        int c = wid * 16 + i;                // 128 chunks of 1024B
        gll16(xsrc + c * 1024 + lane * 16, smem + c * 1024);
    }
    gll16(wp + (wid * 2 + 0) * 1024 + lane * 16, smem + 131072 + (wid * 2 + 0) * 1024);
    gll16(wp + (wid * 2 + 1) * 1024 + lane * 16, smem + 131072 + (wid * 2 + 1) * 1024);
    asm volatile("s_waitcnt vmcnt(0)" ::: "memory");
    __builtin_amdgcn_s_barrier();

    #pragma unroll 2
    for (int t = 0; t < 128; ++t) {
        int p = t & 1;
        if (t < 127) {                       // prefetch B(t+1), stays in flight
            const char* bsrc = wp + (size_t)(t + 1) * 16384;
            char* bdst = smem + 131072 + (p ^ 1) * 16384;
            gll16(bsrc + (wid * 2 + 0) * 1024 + lane * 16, bdst + (wid * 2 + 0) * 1024);
            gll16(bsrc + (wid * 2 + 1) * 1024 + lane * 16, bdst + (wid * 2 + 1) * 1024);
            asm volatile("s_waitcnt vmcnt(2)" ::: "memory");   // B(t) landed
        } else {
            asm volatile("s_waitcnt vmcnt(0)" ::: "memory");
        }
        __builtin_amdgcn_s_barrier();        // B(t) visible to all waves

        int ks32 = t & 15;
        const char* A = smem + (ks32 >> 1) * 16384 + (ks32 & 1) * 8192;
        const char* B = smem + 131072 + p * 16384;
        f16x8 ah[4];
        #pragma unroll
        for (int fr = 0; fr < 4; ++fr)
            ah[fr] = *(const f16x8*)(A + (wr * 4 + fr) * 1024 + lane * 16);
        #pragma unroll
        for (int fc = 0; fc < 4; ++fc) {
            f16x8 bh = *(const f16x8*)(B + (wc * 4 + fc) * 1024 + lane * 16);
            #pragma unroll
            for (int fr = 0; fr < 4; ++fr)
                acc[fr][fc] = __builtin_amdgcn_mfma_f32_16x16x32_f16(ah[fr], bh, acc[fr][fc], 0, 0, 0);
        }

        if (ks32 == 15) {                    // full K done for this cb: top-3 update
            int cb = t >> 4;
            #pragma unroll
            for (int fc = 0; fc < 4; ++fc) {
                unsigned int col = (unsigned)(cb * 256 + wc * 64 + fc * 16 + (lane & 15));
                float wnb = wnorm[col] + 1024.f;   // bias keeps key positive, exp band 2^10
                #pragma unroll
                for (int fr = 0; fr < 4; ++fr) {
                    #pragma unroll
                    for (int reg = 0; reg < 4; ++reg) {
                        float kd = fmaf(-2.f, acc[fr][fc][reg], wnb);
                        unsigned int key = (__float_as_uint(kd) & 0xFFFFF800u) | col;
                        int s = fr * 4 + reg;
                        KINS3(k1[s], k2[s], k3[s], key);
                    }
                    acc[fr][fc] = (f32x4){0.f, 0.f, 0.f, 0.f};
                }
            }
        }
        __builtin_amdgcn_s_barrier();        // reads of buf p done before overwrite
    }

    // butterfly top-3 merge across the 16 column-lanes of each slot
    #pragma unroll
    for (int s = 0; s < 16; ++s) {
        #pragma unroll
        for (int off = 1; off < 16; off <<= 1) {
            unsigned int b1 = (unsigned)__shfl_xor((int)k1[s], off, 16);
            unsigned int b2 = (unsigned)__shfl_xor((int)k2[s], off, 16);
            unsigned int b3 = (unsigned)__shfl_xor((int)k3[s], off, 16);
            MRG3(k1[s], k2[s], k3[s], b1, b2, b3);
        }
    }
    // lane (lane&15)==s owns slot s; static-unrolled select (rule #20)
    unsigned int m1 = 0, m2 = 0, m3 = 0;
    #pragma unroll
    for (int s = 0; s < 16; ++s) {
        bool mine = (lane & 15) == s;
        m1 = mine ? k1[s] : m1;
        m2 = mine ? k2[s] : m2;
        m3 = mine ? k3[s] : m3;
    }
    int sl = lane & 15;
    int rowl = wr * 64 + (sl >> 2) * 16 + (lane >> 4) * 4 + (sl & 3);
    __syncthreads();                         // MFMA loop fully done; reuse A region
    ((uint4*)smem)[rowl * 4 + wc] = make_uint4(m1, m2, m3, 0u);
    __syncthreads();
    if (tid < 128) {
        uint4 a = ((const uint4*)smem)[tid * 4 + 0];
        uint4 b = ((const uint4*)smem)[tid * 4 + 1];
        uint4 c = ((const uint4*)smem)[tid * 4 + 2];
        uint4 d = ((const uint4*)smem)[tid * 4 + 3];
        unsigned int K1 = a.x, K2 = a.y, K3 = a.z;
        MRG3(K1, K2, K3, b.x, b.y, b.z);
        MRG3(K1, K2, K3, c.x, c.y, c.z);
        MRG3(K1, K2, K3, d.x, d.y, d.z);
        float f1 = __uint_as_float(K1 & 0xFFFFF800u) - 1024.f;
        float f2 = __uint_as_float(K2 & 0xFFFFF800u) - 1024.f;
        float f3 = __uint_as_float(K3 & 0xFFFFF800u) - 1024.f;
        int row = rb * 128 + tid;
        idxo[row]   = (int)(K1 & 0x7FFu);
        bestd[row]  = f1;
        cand2o[row] = (f2 - f1 < MARGIN_P) ? (int)(K2 & 0x7FFu) : -1;
        cand3o[row] = (f3 - f1 < MARGIN_P) ? (int)(K3 & 0x7FFu) : -1;
    }
}

// ---------------- kernel 3: fused fp64 refine + gather + loss partial + histogram ----
__global__ __launch_bounds__(256) void k_gather2(const float* __restrict__ x,
                                                 const float* __restrict__ w,
                                                 const int* __restrict__ idxo,
                                                 const int* __restrict__ cand2o,
                                                 const int* __restrict__ cand3o,
                                                 const float* __restrict__ bestd,
                                                 const float* __restrict__ xnorm,
                                                 float* __restrict__ out,
                                                 int* __restrict__ hist,
                                                 double* __restrict__ part) {
    __shared__ double red[4];
    int wid = threadIdx.x >> 6, lane = threadIdx.x & 63;
    int n = blockIdx.x * 4 + wid;
    int c1 = idxo[n];
    int c2 = cand2o[n];
    int cfin = c1;
    double dist = (double)bestd[n];
    if (c2 >= 0) {
        int c3 = cand3o[n];
        int c3e = (c3 < 0) ? c1 : c3;
        const float* xr = x + (size_t)n * DIM;
        const float* w1 = w + (size_t)c1 * DIM;
        const float* w2 = w + (size_t)c2 * DIM;
        const float* w3 = w + (size_t)c3e * DIM;
        double s1 = 0.0, s2 = 0.0, s3 = 0.0;
        #pragma unroll
        for (int j = 0; j < DIM / 64; ++j) {
            int d = lane + 64 * j;
            double xv = (double)xr[d];
            double a = (double)w1[d], b = (double)w2[d], c = (double)w3[d];
            s1 += a * a - 2.0 * xv * a;
            s2 += b * b - 2.0 * xv * b;
            s3 += c * c - 2.0 * xv * c;
        }
        #pragma unroll
        for (int off = 32; off; off >>= 1) {
            s1 += __shfl_xor(s1, off, 64);
            s2 += __shfl_xor(s2, off, 64);
            s3 += __shfl_xor(s3, off, 64);
        }
        double bs = s1; int bi = c1;
        if (s2 < bs || (s2 == bs && c2 < bi)) { bs = s2; bi = c2; }
        if (c3 >= 0 && (s3 < bs || (s3 == bs && c3 < bi))) { bs = s3; bi = c3; }
        cfin = bi;
        dist = bs;
    }
    const float* wq = w + (size_t)cfin * DIM;
    float* oq = out + 1 + (size_t)n * DIM;   // quantized_st == quantized numerically
    #pragma unroll
    for (int j = 0; j < DIM / 64; ++j) {
        int d = j * 64 + lane;
        oq[d] = wq[d];
    }
    if (lane == 0) {
        red[wid] = dist + (double)xnorm[n];  // ||x-w||^2 = (||w||^2-2xw) + ||x||^2
        atomicAdd(&hist[cfin], 1);
        out[2 + NDTOT + n] = (float)cfin;
    }
    __syncthreads();
    if (threadIdx.x == 0)
        part[blockIdx.x] = red[0] + red[1] + red[2] + red[3];
}

// ---------------- kernel 4: deterministic finalize (loss + perplexity) ----------------
__global__ __launch_bounds__(256) void k_final2(const double* __restrict__ part,
                                                const int* __restrict__ hist,
                                                float* __restrict__ out) {
    __shared__ double sm[256];
    int t = threadIdx.x;
    double s = 0.0;
    for (int i = t; i < NROWS / 4; i += 256) s += part[i];
    sm[t] = s; __syncthreads();
    for (int off = 128; off; off >>= 1) { if (t < off) sm[t] += sm[t + off]; __syncthreads(); }
    if (t == 0) out[0] = (float)(sm[0] * 0.25 / (double)NDTOT);
    __syncthreads();
    double e = 0.0;
    for (int k = t; k < KCODES; k += 256) {
        double p = (double)hist[k] / (double)NROWS;
        e -= p * log(p + 1e-10);
    }
    sm[t] = e; __syncthreads();
    for (int off = 128; off; off >>= 1) { if (t < off) sm[t] += sm[t + off]; __syncthreads(); }
    if (t == 0) out[1 + NDTOT] = (float)exp(sm[0]);
}

extern "C" void kernel_launch(void* const* d_in, const int* in_sizes, int n_in,
                              void* d_out, int out_size, void* d_ws, size_t ws_size,
                              hipStream_t stream) {
    const float* x = (const float*)d_in[0];   // [64,1024,512] fp32
    const float* w = (const float*)d_in[1];   // [2048,512] fp32
    float* out = (float*)d_out;
    char* ws = (char*)d_ws;

    // xp (64 MB f16 fragment-ordered) lives in the d_out quantized region:
    // k_gemm consumes it before k_gather2 overwrites every byte with outputs.
    char* xp = (char*)d_out + 16;

    char*   wp    = ws;                            // 2 MB
    float*  wnorm = (float*)(ws + 2097152);        // 8 KB
    int*    idxo  = (int*)(ws + 2105344);          // 256 KB
    int*    cand2 = (int*)(ws + 2367488);          // 256 KB
    int*    cand3 = (int*)(ws + 2629632);          // 256 KB
    int*    hist  = (int*)(ws + 2891776);          // 8 KB
    float*  xnorm = (float*)(ws + 2899968);        // 256 KB
    float*  bestd = (float*)(ws + 3162112);        // 256 KB
    double* part  = (double*)(ws + 3424256);       // 128 KB

    hipMemsetAsync(hist, 0, KCODES * sizeof(int), stream);
    k_prepw  <<<(KCODES * 64) / 256, 256, 0, stream>>>(w, wp, wnorm);
    k_prep   <<<(NROWS * 64) / 256, 256, 0, stream>>>(x, xp, xnorm);
    k_gemm   <<<NROWS / 128, 512, 0, stream>>>(xp, wp, wnorm, idxo, cand2, cand3, bestd);
    k_gather2<<<NROWS / 4, 256, 0, stream>>>(x, w, idxo, cand2, cand3, bestd, xnorm, out, hist, part);
    k_final2 <<<1, 256, 0, stream>>>(part, hist, out);
}